// Round 5
// baseline (88.272 us; speedup 1.0000x reference)
//
#include <hip/hip_runtime.h>
#include <hip/hip_bf16.h>

typedef float f32x4 __attribute__((ext_vector_type(4)));
typedef __bf16 bf16x8 __attribute__((ext_vector_type(8)));

#define INF   8192             // in_features
#define FOLDS 127
#define LOCAL 128
#define OUTF  (FOLDS * LOCAL)  // 16256
#define BM    128

__device__ __forceinline__ bf16x8 load_cvt8(const float* __restrict__ g) {
    f32x4 v0 = *(const f32x4*)g;
    f32x4 v1 = *(const f32x4*)(g + 4);
    bf16x8 w;
    w[0] = (__bf16)v0[0]; w[1] = (__bf16)v0[1]; w[2] = (__bf16)v0[2]; w[3] = (__bf16)v0[3];
    w[4] = (__bf16)v1[0]; w[5] = (__bf16)v1[1]; w[6] = (__bf16)v1[2]; w[7] = (__bf16)v1[3];
    return w;
}

// No LDS, no barriers: each wave loads its MFMA fragments straight from
// global (L2/L3-resident) as fp32, converts to bf16 in-register, MFMAs.
// Wave tiling: 4 waves in 2x2, each owns 64x64 of the block's 128x128 output.
__global__ __launch_bounds__(256, 3)
void local_linear_kernel(const float* __restrict__ x,
                         const float* __restrict__ W,
                         const float* __restrict__ bias,
                         float* __restrict__ out)
{
    const int f  = blockIdx.x;   // fold 0..126
    const int mt = blockIdx.y;   // batch tile 0..15
    const int t  = threadIdx.x;  // 0..255

    const int m0   = mt * BM;
    const int lane = t & 63;
    const int wid  = t >> 6;
    const int wm   = wid >> 1;   // 0..1
    const int wn   = wid & 1;    // 0..1
    const int r16  = lane & 15;
    const int kq   = lane >> 4;  // 0..3

    // wave-local base pointers
    const float* __restrict__ xw = x + (size_t)(m0 + wm * 64) * INF + (size_t)f * 64;
    const float* __restrict__ Ww = W + (size_t)f * (LOCAL * 128) + (size_t)(wn * 64) * 128;

    // bias depends on n only -> fold into accumulator init
    float bv[4];
    #pragma unroll
    for (int j = 0; j < 4; ++j)
        bv[j] = bias[f * LOCAL + wn * 64 + j * 16 + r16];

    f32x4 acc[4][4];
    #pragma unroll
    for (int i = 0; i < 4; ++i)
        #pragma unroll
        for (int j = 0; j < 4; ++j)
            acc[i][j] = (f32x4){bv[j], bv[j], bv[j], bv[j]};

    // K = 128 in 4 slices of 32; fragments loaded direct from global.
    // A frag lane map: row m = i*16 + r16, k = ks*32 + kq*8 (+0..7)
    // B frag lane map: row n = j*16 + r16, same k  (W is [l][k], k-contiguous)
    #pragma unroll
    for (int ks = 0; ks < 4; ++ks) {
        const int kof = ks * 32 + kq * 8;
        bf16x8 a[4], b[4];
        #pragma unroll
        for (int i = 0; i < 4; ++i)
            a[i] = load_cvt8(xw + (size_t)(i * 16 + r16) * INF + kof);
        #pragma unroll
        for (int j = 0; j < 4; ++j)
            b[j] = load_cvt8(Ww + (j * 16 + r16) * 128 + kof);
        #pragma unroll
        for (int i = 0; i < 4; ++i)
            #pragma unroll
            for (int j = 0; j < 4; ++j)
                acc[i][j] = __builtin_amdgcn_mfma_f32_16x16x32_bf16(a[i], b[j], acc[i][j], 0, 0, 0);
    }

    // epilogue: plain fp32 stores (bias already in acc)
    // C/D map: n = lane&15, m = (lane>>4)*4 + reg
    #pragma unroll
    for (int i = 0; i < 4; ++i) {
        const int mrow = m0 + wm * 64 + i * 16 + kq * 4;
        #pragma unroll
        for (int j = 0; j < 4; ++j) {
            const int ncol = f * LOCAL + wn * 64 + j * 16 + r16;
            float* o = out + (size_t)mrow * OUTF + ncol;
            #pragma unroll
            for (int r = 0; r < 4; ++r)
                o[(size_t)r * OUTF] = acc[i][j][r];
        }
    }
}

extern "C" void kernel_launch(void* const* d_in, const int* in_sizes, int n_in,
                              void* d_out, int out_size, void* d_ws, size_t ws_size,
                              hipStream_t stream) {
    const float* x    = (const float*)d_in[0];
    const float* W    = (const float*)d_in[1];
    const float* bias = (const float*)d_in[2];
    float* out        = (float*)d_out;

    dim3 grid(FOLDS, 2048 / BM);   // 127 x 16 = 2032 blocks
    dim3 block(256);
    local_linear_kernel<<<grid, block, 0, stream>>>(x, W, bias, out);
}

// Round 6
// 50.656 us; speedup vs baseline: 1.7426x; 1.7426x over previous
//
#include <hip/hip_runtime.h>
#include <hip/hip_bf16.h>

typedef float f32x4 __attribute__((ext_vector_type(4)));
typedef __bf16 bf16x8 __attribute__((ext_vector_type(8)));

#define INF   8192             // in_features
#define FOLDS 127
#define LOCAL 128
#define OUTF  (FOLDS * LOCAL)  // 16256
#define BM    128

// W bf16 scratch: 127*128*128 bf16 = 4,161,536 bytes
#define WB_BYTES ((size_t)FOLDS * LOCAL * 128 * 2)

__global__ void convert_w_kernel(const float* __restrict__ W, __bf16* __restrict__ Wb) {
    const size_t i = ((size_t)blockIdx.x * 256 + threadIdx.x) * 8;
    f32x4 v0 = *(const f32x4*)(W + i);
    f32x4 v1 = *(const f32x4*)(W + i + 4);
    bf16x8 w;
    w[0] = (__bf16)v0[0]; w[1] = (__bf16)v0[1]; w[2] = (__bf16)v0[2]; w[3] = (__bf16)v0[3];
    w[4] = (__bf16)v1[0]; w[5] = (__bf16)v1[1]; w[6] = (__bf16)v1[2]; w[7] = (__bf16)v1[3];
    *(bf16x8*)(Wb + i) = w;
}

__device__ __forceinline__ void cvt_store8(char* lds, int byte, f32x4 v0, f32x4 v1) {
    bf16x8 w;
    w[0] = (__bf16)v0[0]; w[1] = (__bf16)v0[1]; w[2] = (__bf16)v0[2]; w[3] = (__bf16)v0[3];
    w[4] = (__bf16)v1[0]; w[5] = (__bf16)v1[1]; w[6] = (__bf16)v1[2]; w[7] = (__bf16)v1[3];
    *(bf16x8*)(lds + byte) = w;
}

// As/Bs: 128 rows x 128 cols bf16 (row stride 256B), XOR swizzle byte ^= (row&7)<<4
template<bool WBF16>
__global__ __launch_bounds__(256, 2)
void local_linear_kernel(const float* __restrict__ x,
                         const float* __restrict__ Wf32,
                         const __bf16* __restrict__ Wbf,
                         const float* __restrict__ bias,
                         float* __restrict__ out)
{
    __shared__ __align__(16) __bf16 As[128 * 128];   // 32 KiB
    __shared__ __align__(16) __bf16 Bs[128 * 128];   // 32 KiB

    const int mt = blockIdx.x;   // batch tile 0..15
    const int f  = blockIdx.y;   // fold 0..126
    const int t  = threadIdx.x;  // 0..255

    const int m0   = mt * BM;
    const int lane = t & 63;
    const int wid  = t >> 6;
    const int wm   = wid >> 1;   // 0..1
    const int wn   = wid & 1;    // 0..1
    const int r16  = lane & 15;
    const int kq   = lane >> 4;  // 0..3

    // ---- stage W fold -> Bs ----
    if constexpr (WBF16) {
        // bf16 W: fire-and-forget global_load_lds, inverse swizzle on SOURCE,
        // linear LDS dest (wave-uniform base + lane*16).
        const char* Wsrc = (const char*)(Wbf + (size_t)f * LOCAL * 128);
        #pragma unroll
        for (int c = 0; c < 8; ++c) {
            const int base  = wid * 8192 + c * 1024;   // wave-uniform LDS byte base
            const int b     = base + lane * 16;        // this lane's linear dest byte
            const int row   = b >> 8;
            const int inner = b & 255;
            const int srcb  = row * 256 + (inner ^ ((row & 7) << 4));
            __builtin_amdgcn_global_load_lds(
                (const __attribute__((address_space(1))) void*)(Wsrc + srcb),
                (__attribute__((address_space(3))) void*)((char*)Bs + base),
                16, 0, 0);
        }
    } else {
        // fallback: fp32 W, reg-stage + convert (exact R1 path)
        const float* Wf = Wf32 + (size_t)f * (LOCAL * 128);
        #pragma unroll
        for (int it = 0; it < 8; ++it) {
            const int e   = it * 2048 + t * 8;
            const int row = e >> 7;
            const int col = e & 127;
            const float* g = Wf + row * 128 + col;
            f32x4 v0 = *(const f32x4*)g;
            f32x4 v1 = *(const f32x4*)(g + 4);
            cvt_store8((char*)Bs, (row * 256 + col * 2) ^ ((row & 7) << 4), v0, v1);
        }
    }

    // ---- stage x tile -> As (fp32 -> bf16, swizzled; overlaps with B loads) ----
    const float* __restrict__ xg = x + (size_t)m0 * INF + (size_t)f * 64;
    #pragma unroll
    for (int it = 0; it < 8; ++it) {
        const int e   = it * 2048 + t * 8;
        const int row = e >> 7;
        const int col = e & 127;
        const float* g = xg + (size_t)row * INF + col;
        f32x4 v0 = *(const f32x4*)g;
        f32x4 v1 = *(const f32x4*)(g + 4);
        cvt_store8((char*)As, (row * 256 + col * 2) ^ ((row & 7) << 4), v0, v1);
    }
    __syncthreads();

    // ---- bias folded into accumulator init (bias depends on n only) ----
    float bv[4];
    #pragma unroll
    for (int j = 0; j < 4; ++j)
        bv[j] = bias[f * LOCAL + wn * 64 + j * 16 + r16];

    f32x4 acc[4][4];
    #pragma unroll
    for (int i = 0; i < 4; ++i)
        #pragma unroll
        for (int j = 0; j < 4; ++j)
            acc[i][j] = (f32x4){bv[j], bv[j], bv[j], bv[j]};

    // ---- compute: 4 waves in 2x2 grid, each 64x64 output ----
    #pragma unroll
    for (int ks = 0; ks < 4; ++ks) {
        const int kof = ks * 32 + kq * 8;
        bf16x8 a[4], b[4];
        #pragma unroll
        for (int i = 0; i < 4; ++i) {
            const int row  = wm * 64 + i * 16 + r16;
            const int byte = (row * 256 + kof * 2) ^ ((row & 7) << 4);
            a[i] = *(const bf16x8*)((const char*)As + byte);
        }
        #pragma unroll
        for (int j = 0; j < 4; ++j) {
            const int row  = wn * 64 + j * 16 + r16;
            const int byte = (row * 256 + kof * 2) ^ ((row & 7) << 4);
            b[j] = *(const bf16x8*)((const char*)Bs + byte);
        }
        #pragma unroll
        for (int i = 0; i < 4; ++i)
            #pragma unroll
            for (int j = 0; j < 4; ++j)
                acc[i][j] = __builtin_amdgcn_mfma_f32_16x16x32_bf16(a[i], b[j], acc[i][j], 0, 0, 0);
    }

    // ---- epilogue: plain fp32 stores (bias already in acc) ----
    // C/D map: n = lane&15, m = (lane>>4)*4 + reg
    #pragma unroll
    for (int i = 0; i < 4; ++i) {
        const int mrow = m0 + wm * 64 + i * 16 + kq * 4;
        #pragma unroll
        for (int j = 0; j < 4; ++j) {
            const int ncol = f * LOCAL + wn * 64 + j * 16 + r16;
            float* o = out + (size_t)mrow * OUTF + ncol;
            #pragma unroll
            for (int r = 0; r < 4; ++r)
                o[(size_t)r * OUTF] = acc[i][j][r];
        }
    }
}

extern "C" void kernel_launch(void* const* d_in, const int* in_sizes, int n_in,
                              void* d_out, int out_size, void* d_ws, size_t ws_size,
                              hipStream_t stream) {
    const float* x    = (const float*)d_in[0];
    const float* W    = (const float*)d_in[1];
    const float* bias = (const float*)d_in[2];
    float* out        = (float*)d_out;

    dim3 grid(2048 / BM, FOLDS);   // 16 x 127, blockIdx.x = batch tile (R1 layout)
    dim3 block(256);

    if (ws_size >= WB_BYTES) {
        __bf16* Wb = (__bf16*)d_ws;
        convert_w_kernel<<<1016, 256, 0, stream>>>(W, Wb);   // 1016*256*8 = 2,080,768 elems
        local_linear_kernel<true><<<grid, block, 0, stream>>>(x, W, Wb, bias, out);
    } else {
        local_linear_kernel<false><<<grid, block, 0, stream>>>(x, W, nullptr, bias, out);
    }
}

// Round 7
// 49.421 us; speedup vs baseline: 1.7861x; 1.0250x over previous
//
#include <hip/hip_runtime.h>
#include <hip/hip_bf16.h>

typedef float f32x4 __attribute__((ext_vector_type(4)));
typedef __bf16 bf16x8 __attribute__((ext_vector_type(8)));

#define INF   8192             // in_features
#define FOLDS 127
#define LOCAL 128
#define OUTF  (FOLDS * LOCAL)  // 16256
#define BM    128
#define NWG   (FOLDS * 16)     // 2032, divisible by 8 XCDs -> 254 per XCD

// As/Bs: 128 rows x 128 cols bf16 (row stride 256B), XOR swizzle byte ^= (row&7)<<4
__device__ __forceinline__ void cvt_store8(char* lds, int byte, f32x4 v0, f32x4 v1) {
    bf16x8 w;
    w[0] = (__bf16)v0[0]; w[1] = (__bf16)v0[1]; w[2] = (__bf16)v0[2]; w[3] = (__bf16)v0[3];
    w[4] = (__bf16)v1[0]; w[5] = (__bf16)v1[1]; w[6] = (__bf16)v1[2]; w[7] = (__bf16)v1[3];
    *(bf16x8*)(lds + byte) = w;
}

__global__ __launch_bounds__(256, 2)
void local_linear_kernel(const float* __restrict__ x,
                         const float* __restrict__ W,
                         const float* __restrict__ bias,
                         float* __restrict__ out)
{
    __shared__ __align__(16) __bf16 As[128 * 128];   // 32 KiB
    __shared__ __align__(16) __bf16 Bs[128 * 128];   // 32 KiB

    // XCD-aware bijective swizzle (T1/m204): hardware round-robins
    // consecutive blockIdx across the 8 XCDs; remap so each XCD gets a
    // contiguous run of tiles ordered fold-major. All 16 batch-tiles of a
    // fold (shared W) and consecutive folds (overlapping x cols) then hit
    // the same XCD's L2.
    const int bid = blockIdx.x;
    const int d   = (bid & 7) * (NWG / 8) + (bid >> 3);
    const int f   = d >> 4;     // fold 0..126
    const int mt  = d & 15;     // batch tile 0..15
    const int t   = threadIdx.x;

    const int m0   = mt * BM;
    const int lane = t & 63;
    const int wid  = t >> 6;
    const int wm   = wid >> 1;   // 0..1
    const int wn   = wid & 1;    // 0..1
    const int r16  = lane & 15;
    const int kq   = lane >> 4;  // 0..3

    // ---- stage W fold -> Bs (fp32 -> bf16, swizzled) ----
    const float* __restrict__ Wf = W + (size_t)f * (LOCAL * 128);
    #pragma unroll
    for (int it = 0; it < 8; ++it) {
        const int e   = it * 2048 + t * 8;
        const int row = e >> 7;        // l (output feature)
        const int col = e & 127;       // k
        const float* g = Wf + row * 128 + col;
        f32x4 v0 = *(const f32x4*)g;
        f32x4 v1 = *(const f32x4*)(g + 4);
        cvt_store8((char*)Bs, (row * 256 + col * 2) ^ ((row & 7) << 4), v0, v1);
    }

    // ---- stage x tile -> As (fp32 -> bf16, swizzled) ----
    const float* __restrict__ xg = x + (size_t)m0 * INF + (size_t)f * 64;
    #pragma unroll
    for (int it = 0; it < 8; ++it) {
        const int e   = it * 2048 + t * 8;
        const int row = e >> 7;        // batch row within tile
        const int col = e & 127;       // k
        const float* g = xg + (size_t)row * INF + col;
        f32x4 v0 = *(const f32x4*)g;
        f32x4 v1 = *(const f32x4*)(g + 4);
        cvt_store8((char*)As, (row * 256 + col * 2) ^ ((row & 7) << 4), v0, v1);
    }
    __syncthreads();

    // ---- bias folded into accumulator init (bias depends on n only) ----
    float bv[4];
    #pragma unroll
    for (int j = 0; j < 4; ++j)
        bv[j] = bias[f * LOCAL + wn * 64 + j * 16 + r16];

    f32x4 acc[4][4];
    #pragma unroll
    for (int i = 0; i < 4; ++i)
        #pragma unroll
        for (int j = 0; j < 4; ++j)
            acc[i][j] = (f32x4){bv[j], bv[j], bv[j], bv[j]};

    // ---- compute: 4 waves in 2x2 grid, each 64x64 output ----
    #pragma unroll
    for (int ks = 0; ks < 4; ++ks) {
        const int kof = ks * 32 + kq * 8;
        bf16x8 a[4], b[4];
        #pragma unroll
        for (int i = 0; i < 4; ++i) {
            const int row  = wm * 64 + i * 16 + r16;
            const int byte = (row * 256 + kof * 2) ^ ((row & 7) << 4);
            a[i] = *(const bf16x8*)((const char*)As + byte);
        }
        #pragma unroll
        for (int j = 0; j < 4; ++j) {
            const int row  = wn * 64 + j * 16 + r16;
            const int byte = (row * 256 + kof * 2) ^ ((row & 7) << 4);
            b[j] = *(const bf16x8*)((const char*)Bs + byte);
        }
        #pragma unroll
        for (int i = 0; i < 4; ++i)
            #pragma unroll
            for (int j = 0; j < 4; ++j)
                acc[i][j] = __builtin_amdgcn_mfma_f32_16x16x32_bf16(a[i], b[j], acc[i][j], 0, 0, 0);
    }

    // ---- epilogue: plain fp32 stores (bias already in acc) ----
    // C/D map: n = lane&15, m = (lane>>4)*4 + reg
    #pragma unroll
    for (int i = 0; i < 4; ++i) {
        const int mrow = m0 + wm * 64 + i * 16 + kq * 4;
        #pragma unroll
        for (int j = 0; j < 4; ++j) {
            const int ncol = f * LOCAL + wn * 64 + j * 16 + r16;
            float* o = out + (size_t)mrow * OUTF + ncol;
            #pragma unroll
            for (int r = 0; r < 4; ++r)
                o[(size_t)r * OUTF] = acc[i][j][r];
        }
    }
}

extern "C" void kernel_launch(void* const* d_in, const int* in_sizes, int n_in,
                              void* d_out, int out_size, void* d_ws, size_t ws_size,
                              hipStream_t stream) {
    const float* x    = (const float*)d_in[0];
    const float* W    = (const float*)d_in[1];
    const float* bias = (const float*)d_in[2];
    float* out        = (float*)d_out;

    dim3 grid(NWG);   // 2032 blocks, 1-D, XCD-swizzled inside the kernel
    dim3 block(256);
    local_linear_kernel<<<grid, block, 0, stream>>>(x, W, bias, out);
}

// Round 8
// 46.810 us; speedup vs baseline: 1.8857x; 1.0558x over previous
//
#include <hip/hip_runtime.h>
#include <hip/hip_bf16.h>

typedef float f32x4 __attribute__((ext_vector_type(4)));
typedef __bf16 bf16x8 __attribute__((ext_vector_type(8)));

#define INF   8192             // in_features
#define FOLDS 127
#define LOCAL 128
#define OUTF  (FOLDS * LOCAL)  // 16256
#define BM    64               // batch rows per block
#define BN    64               // output features per block (half a fold)

// As/Bs: 64 rows x 128 cols bf16 (row stride 256B), XOR swizzle byte ^= (row&7)<<4
__device__ __forceinline__ void cvt_store8(char* lds, int byte, f32x4 v0, f32x4 v1) {
    bf16x8 w;
    w[0] = (__bf16)v0[0]; w[1] = (__bf16)v0[1]; w[2] = (__bf16)v0[2]; w[3] = (__bf16)v0[3];
    w[4] = (__bf16)v1[0]; w[5] = (__bf16)v1[1]; w[6] = (__bf16)v1[2]; w[7] = (__bf16)v1[3];
    *(bf16x8*)(lds + byte) = w;
}

__global__ __launch_bounds__(256, 5)   // 32 KB LDS -> 5 blocks/CU, 20 waves/CU
void local_linear_kernel(const float* __restrict__ x,
                         const float* __restrict__ W,
                         const float* __restrict__ bias,
                         float* __restrict__ out)
{
    __shared__ __align__(16) __bf16 As[BM * 128];   // 16 KiB
    __shared__ __align__(16) __bf16 Bs[BN * 128];   // 16 KiB

    const int mt = blockIdx.x;          // batch tile 0..31
    const int fn = blockIdx.y;          // fold-half 0..253
    const int f  = fn >> 1;             // fold 0..126
    const int bn0 = (fn & 1) * BN;      // 0 or 64 within the fold's 128 outputs
    const int t  = threadIdx.x;         // 0..255

    const int m0   = mt * BM;
    const int lane = t & 63;
    const int wid  = t >> 6;
    const int wm   = wid >> 1;   // 0..1 (32 rows each)
    const int wn   = wid & 1;    // 0..1 (32 cols each)
    const int r16  = lane & 15;
    const int kq   = lane >> 4;  // 0..3

    // ---- stage W half-fold -> Bs (fp32 -> bf16, swizzled): 64x128, 4 iters ----
    const float* __restrict__ Wf = W + (size_t)f * (LOCAL * 128) + (size_t)bn0 * 128;
    #pragma unroll
    for (int it = 0; it < 4; ++it) {
        const int e   = it * 2048 + t * 8;
        const int row = e >> 7;        // l within half-fold (0..63)
        const int col = e & 127;       // k
        const float* g = Wf + row * 128 + col;
        f32x4 v0 = *(const f32x4*)g;
        f32x4 v1 = *(const f32x4*)(g + 4);
        cvt_store8((char*)Bs, (row * 256 + col * 2) ^ ((row & 7) << 4), v0, v1);
    }

    // ---- stage x tile -> As (fp32 -> bf16, swizzled): 64x128, 4 iters ----
    const float* __restrict__ xg = x + (size_t)m0 * INF + (size_t)f * 64;
    #pragma unroll
    for (int it = 0; it < 4; ++it) {
        const int e   = it * 2048 + t * 8;
        const int row = e >> 7;        // batch row within tile (0..63)
        const int col = e & 127;       // k
        const float* g = xg + (size_t)row * INF + col;
        f32x4 v0 = *(const f32x4*)g;
        f32x4 v1 = *(const f32x4*)(g + 4);
        cvt_store8((char*)As, (row * 256 + col * 2) ^ ((row & 7) << 4), v0, v1);
    }
    __syncthreads();

    // ---- bias folded into accumulator init (bias depends on n only) ----
    float bv[2];
    #pragma unroll
    for (int j = 0; j < 2; ++j)
        bv[j] = bias[f * LOCAL + bn0 + wn * 32 + j * 16 + r16];

    f32x4 acc[2][2];
    #pragma unroll
    for (int i = 0; i < 2; ++i)
        #pragma unroll
        for (int j = 0; j < 2; ++j)
            acc[i][j] = (f32x4){bv[j], bv[j], bv[j], bv[j]};

    // ---- compute: 4 waves in 2x2, each 32x32 output; 4 MFMA per k-slice ----
    #pragma unroll
    for (int ks = 0; ks < 4; ++ks) {
        const int kof = ks * 32 + kq * 8;
        bf16x8 a[2], b[2];
        #pragma unroll
        for (int i = 0; i < 2; ++i) {
            const int row  = wm * 32 + i * 16 + r16;
            const int byte = (row * 256 + kof * 2) ^ ((row & 7) << 4);
            a[i] = *(const bf16x8*)((const char*)As + byte);
        }
        #pragma unroll
        for (int j = 0; j < 2; ++j) {
            const int row  = wn * 32 + j * 16 + r16;
            const int byte = (row * 256 + kof * 2) ^ ((row & 7) << 4);
            b[j] = *(const bf16x8*)((const char*)Bs + byte);
        }
        #pragma unroll
        for (int i = 0; i < 2; ++i)
            #pragma unroll
            for (int j = 0; j < 2; ++j)
                acc[i][j] = __builtin_amdgcn_mfma_f32_16x16x32_bf16(a[i], b[j], acc[i][j], 0, 0, 0);
    }

    // ---- epilogue: plain fp32 stores (bias already in acc) ----
    // C/D map: n = lane&15, m = (lane>>4)*4 + reg
    #pragma unroll
    for (int i = 0; i < 2; ++i) {
        const int mrow = m0 + wm * 32 + i * 16 + kq * 4;
        #pragma unroll
        for (int j = 0; j < 2; ++j) {
            const int ncol = f * LOCAL + bn0 + wn * 32 + j * 16 + r16;
            float* o = out + (size_t)mrow * OUTF + ncol;
            #pragma unroll
            for (int r = 0; r < 4; ++r)
                o[(size_t)r * OUTF] = acc[i][j][r];
        }
    }
}

extern "C" void kernel_launch(void* const* d_in, const int* in_sizes, int n_in,
                              void* d_out, int out_size, void* d_ws, size_t ws_size,
                              hipStream_t stream) {
    const float* x    = (const float*)d_in[0];
    const float* W    = (const float*)d_in[1];
    const float* bias = (const float*)d_in[2];
    float* out        = (float*)d_out;

    dim3 grid(2048 / BM, FOLDS * 2);   // 32 x 254 = 8128 blocks
    dim3 block(256);
    local_linear_kernel<<<grid, block, 0, stream>>>(x, W, bias, out);
}